// Round 3
// baseline (310.227 us; speedup 1.0000x reference)
//
#include <hip/hip_runtime.h>
#include <math.h>

// Problem constants
constexpr int BQ = 32;       // query batch
constexpr int C  = 256;      // channels
constexpr int HW = 4096;     // 64*64
constexpr int W  = 64;
constexpr int P  = 256;      // protos (4 * 8 * 8)
constexpr float THRESH = 0.95f;
constexpr float SCALE  = 20.0f;
constexpr float EPSF   = 1e-4f;
constexpr double EPSD  = 1e-4;
constexpr float GAP_THRESH = 2e-3f;   // split-bf16 dist err ~5e-4 -> 4x margin
constexpr int MAXSUS = 65536;

// d_out layout: pred [0, 131072) | debug_assign [131072, 262144) | proto_grid [262144, 278528)
constexpr int OUT_ASSIGN = BQ * HW;
constexpr int OUT_GRID   = 2 * BQ * HW;

typedef __attribute__((ext_vector_type(8))) short short8;
typedef __attribute__((ext_vector_type(4))) float floatx4;
typedef __attribute__((ext_vector_type(4))) unsigned int uint4v;

static __device__ __forceinline__ unsigned short f2bf(float x) {
    unsigned u = __float_as_uint(x);
    u += 0x7FFFu + ((u >> 16) & 1u);     // round-to-nearest-even (no NaN inputs)
    return (unsigned short)(u >> 16);
}
static __device__ __forceinline__ float bf2f(unsigned short h) {
    return __uint_as_float(((unsigned)h) << 16);
}

// Fragment-order offset (ushort units): [tile][ks][h][lane][j], lane = quad*16 + idx,
// element j of lane <-> k = ks*32 + quad*8 + j. A and B use the IDENTICAL map, so
// any k-permutation cancels in the MFMA contraction.
#define FRAGOFF(tile, ks, h, lane) (((((tile) * 8 + (ks)) * 2 + (h)) * 64 + (lane)) * 8)

// async global->LDS, 16 B/lane; LDS dest = wave-uniform base + lane*16
static __device__ __forceinline__ void gl_lds16(const unsigned short* gp, unsigned short* lp) {
    __builtin_amdgcn_global_load_lds(
        (const __attribute__((address_space(1))) unsigned int*)gp,
        (__attribute__((address_space(3))) unsigned int*)lp, 16, 0, 0);
}

// ---------------------------------------------------------------------------
// Prep: pooled protos (fp64 normalize) -> split-bf16 frag-order pB + fp64 pn64,
// valid flags, proto_grid output, zero suspect counter. Block=proto, thread=channel.
// ---------------------------------------------------------------------------
__global__ __launch_bounds__(256)
void prep_kernel(const float* __restrict__ sup_x, const float* __restrict__ sup_y,
                 float* __restrict__ out, unsigned short* __restrict__ pB,
                 double* __restrict__ pn64, int* __restrict__ valid,
                 int* __restrict__ counter)
{
    const int p = blockIdx.x;     // proto index = s*64 + gy*8 + gx
    const int t = threadIdx.x;    // channel
    const int s = p >> 6, gy = (p >> 3) & 7, gx = p & 7;

    const float* base = sup_x + ((size_t)(s * C + t)) * HW + (gy * 8) * W + gx * 8;
    double sum = 0.0;
#pragma unroll
    for (int r = 0; r < 8; ++r) {
        const float4 a  = *(const float4*)(base + r * W);
        const float4 bq = *(const float4*)(base + r * W + 4);
        sum += (double)a.x;  sum += (double)a.y;  sum += (double)a.z;  sum += (double)a.w;
        sum += (double)bq.x; sum += (double)bq.y; sum += (double)bq.z; sum += (double)bq.w;
    }
    const double mean = sum * (1.0 / 64.0);

    __shared__ double red[256];
    red[t] = mean * mean;
    __syncthreads();
    for (int off = 128; off > 0; off >>= 1) {
        if (t < off) red[t] += red[t + off];
        __syncthreads();
    }
    const double nrm = sqrt(red[0]);
    const double pnv = mean / fmax(nrm, EPSD);
    pn64[(size_t)p * C + t] = pnv;

    // split-bf16 frag-order store: nt=p>>4, n-idx=p&15; ks=c>>5, quad=(c>>3)&3, j=c&7
    const float pnf = (float)pnv;
    const unsigned short phi = f2bf(pnf);
    const unsigned short plo = f2bf(pnf - bf2f(phi));
    const int nt = p >> 4, ks = t >> 5, lane = (((t >> 3) & 3) << 4) | (p & 15), j = t & 7;
    pB[FRAGOFF(nt, ks, 0, lane) + j] = phi;
    pB[FRAGOFF(nt, ks, 1, lane) + j] = plo;

    bool mybit = false;
    if (t < 64) {
        const int r = t >> 3, k = t & 7;
        mybit = sup_y[s * HW + (gy * 8 + r) * W + gx * 8 + k] > THRESH;
    }
    const unsigned long long bm = __ballot(mybit);   // wave 0 carries t=0..63
    if (t == 0) {
        valid[p] = (__popcll(bm) > 32) ? 1 : 0;      // mask_pooled > 0.5
        if (p == 0) *counter = 0;
    }
    if (t < 64) {
        const int i = p * 64 + t;
        out[OUT_GRID + i] = (sup_y[i] > THRESH) ? 1.0f : 0.0f;
    }
}

// ---------------------------------------------------------------------------
// Main: split-bf16 MFMA dists + fused softmax/argmax/pred.
// Block = 64 positions (4 waves); wave w owns pos-tile w (16 pos) x ALL 256 protos.
//
// R3 changes (on top of R2's occupancy win, 135->87 us):
// (1) COUNTED VMCNT + RAW BARRIERS (T4/m201 pattern). R2's __syncthreads() at
//     barrier (b) implicitly drained vmcnt(0) -- including the A(ks+1) HBM
//     prefetch issued moments earlier -> ~600-900 cyc exposed stall per ks.
//     Now: stage B(ks) [8 gl_lds, OLDEST] ... prefetch A(ks+1) [8 loads,
//     NEWEST] ... s_waitcnt vmcnt(8) [waits oldest 8 = B only, m135 in-order
//     semantics] + raw s_barrier. A prefetch stays in flight across the
//     barrier and lands under the ~1200-cyc MFMA section. sched_barrier(0)
//     pins issue order around the asm. ks==7 uses vmcnt(0) (no prefetch).
//     Barrier (a) is raw (each wave's ds_reads already retired: MFMA consumed
//     them); iteration 0 keeps a full __syncthreads (validLds visibility).
// (2) v_cvt_pk_bf16_f32 conversion (T12 recipe): 2 elems/instr instead of
//     ~11 VALU/elem bit math. cvt_pk rounding mode is irrelevant: lo =
//     cvt(v - hi) compensates any hi rounding; residual bound unchanged, so
//     GAP_THRESH margin holds.
// launch_bounds(256,4): 64 arch VGPR + 64 AGPR acc -> 4 waves/SIMD, 4 blocks/CU
// (LDS 33.8 KB x 4 = 135 KB).
// ---------------------------------------------------------------------------
__global__ __launch_bounds__(256, 4)
void dist_kernel(const float* __restrict__ qry, const unsigned short* __restrict__ pB,
                 const int* __restrict__ valid, float* __restrict__ out,
                 int* __restrict__ counter, int* __restrict__ suspects)
{
    __shared__ unsigned short ldsB[16 * 2 * 64 * 8];   // 32 KiB: [nt][h][lane][j]
    __shared__ int validLds[P];                        // 1 KiB

    const int t    = threadIdx.x;
    const int w    = t >> 6;      // wave -> pos-tile
    const int l    = t & 63;
    const int quad = l >> 4;
    const int m    = l & 15;

    const int b    = blockIdx.x >> 6;
    const int pos0 = (blockIdx.x & 63) * 64;

    validLds[t] = valid[t];

    // lane l covers pos = pos0 + w*16 + m, k = ks*32 + quad*8 + j
    const float* qp = qry + (size_t)b * C * HW + pos0 + w * 16 + m;

    floatx4 acc[16];
#pragma unroll
    for (int nt = 0; nt < 16; ++nt) acc[nt] = (floatx4){0.f, 0.f, 0.f, 0.f};

    // prologue: issue A loads for ks=0
    float vbuf[8];
#pragma unroll
    for (int j = 0; j < 8; ++j)
        vbuf[j] = qp[(size_t)(quad * 8 + j) * HW];

    float ssq = 0.f;
#pragma unroll
    for (int ks = 0; ks < 8; ++ks) {
        // (a) all waves done reading ldsB(ks-1); iter 0 also covers validLds write
        if (ks == 0) __syncthreads();
        else         __builtin_amdgcn_s_barrier();

        // stage B(ks): 32 chunks of 1 KiB; wave w stages chunks w*8..w*8+7  [OLDEST 8 vmem]
#pragma unroll
        for (int i = 0; i < 8; ++i) {
            const int idx = w * 8 + i, nt = idx >> 1, h = idx & 1;
            gl_lds16(pB + FRAGOFF(nt, ks, h, 0) + l * 8,
                     &ldsB[(nt * 2 + h) * 512]);
        }

        // convert A(ks) from vbuf via v_cvt_pk_bf16_f32 (compiler inserts the
        // precise vmcnt wait for the vbuf loads here; straight-line after unroll)
        uint4v hu, lu;
#pragma unroll
        for (int j = 0; j < 8; j += 2) {
            const float v0 = vbuf[j], v1 = vbuf[j + 1];
            ssq = fmaf(v0, v0, ssq);
            ssq = fmaf(v1, v1, ssq);
            unsigned hi2;
            asm("v_cvt_pk_bf16_f32 %0, %1, %2" : "=v"(hi2) : "v"(v0), "v"(v1));
            const float r0 = v0 - __uint_as_float(hi2 << 16);
            const float r1 = v1 - __uint_as_float(hi2 & 0xffff0000u);
            unsigned lo2;
            asm("v_cvt_pk_bf16_f32 %0, %1, %2" : "=v"(lo2) : "v"(r0), "v"(r1));
            hu[j >> 1] = hi2;
            lu[j >> 1] = lo2;
        }
        const short8 h8 = __builtin_bit_cast(short8, hu);
        const short8 l8 = __builtin_bit_cast(short8, lu);

        // prefetch A(ks+1)  [NEWEST 8 vmem; stays in flight across the barrier]
        if (ks < 7) {
#pragma unroll
            for (int j = 0; j < 8; ++j)
                vbuf[j] = qp[(size_t)((ks + 1) * 32 + quad * 8 + j) * HW];
        }

        // (b) wait ONLY the B stage (oldest 8), then sync; A prefetch uncounted
        __builtin_amdgcn_sched_barrier(0);   // pin all prior issues above the wait
        if (ks < 7) asm volatile("s_waitcnt vmcnt(8)" ::: "memory");
        else        asm volatile("s_waitcnt vmcnt(0)" ::: "memory");
        __builtin_amdgcn_s_barrier();
        __builtin_amdgcn_sched_barrier(0);   // keep ds_reads below the barrier

#pragma unroll
        for (int nt = 0; nt < 16; ++nt) {
            const short8 bh = *(const short8*)&ldsB[((nt * 2 + 0) * 64 + l) * 8];
            const short8 bl = *(const short8*)&ldsB[((nt * 2 + 1) * 64 + l) * 8];
            acc[nt] = __builtin_amdgcn_mfma_f32_16x16x32_bf16(h8, bh, acc[nt], 0, 0, 0);
            acc[nt] = __builtin_amdgcn_mfma_f32_16x16x32_bf16(h8, bl, acc[nt], 0, 0, 0);
            acc[nt] = __builtin_amdgcn_mfma_f32_16x16x32_bf16(l8, bh, acc[nt], 0, 0, 0);
        }
    }

    // ||q||^2 for pos w*16+m: sum the 4 quads (lanes differing in bits 4,5)
    ssq += __shfl_xor(ssq, 16);
    ssq += __shfl_xor(ssq, 32);
    const float scalev = SCALE / fmaxf(sqrtf(ssq), EPSF);

    // ---- epilogue (wave-local). C/D: proto = nt*16 + m, pos-in-tile = quad*4 + r ----
    int vbits = 0;
#pragma unroll
    for (int nt = 0; nt < 16; ++nt) vbits |= validLds[nt * 16 + m] << nt;

    float scr[4];
#pragma unroll
    for (int r = 0; r < 4; ++r) scr[r] = __shfl(scalev, quad * 4 + r);   // lane quad*4+r holds pos w*16+quad*4+r
#pragma unroll
    for (int nt = 0; nt < 16; ++nt)
#pragma unroll
        for (int r = 0; r < 4; ++r) acc[nt][r] *= scr[r];   // positive factor: ordering-safe

#pragma unroll
    for (int r = 0; r < 4; ++r) {
        // pass 1: max / argmax (first occurrence) / 2nd-max
        float m1 = -INFINITY, m2 = -INFINITY; int id = 0x7fffffff;
#pragma unroll
        for (int nt = 0; nt < 16; ++nt) {
            if (vbits & (1 << nt)) {
                const float d = acc[nt][r];
                if (d > m1)      { m2 = m1; m1 = d; id = nt * 16 + m; }
                else if (d > m2) { m2 = d; }
            }
        }
#pragma unroll
        for (int sh = 1; sh < 16; sh <<= 1) {   // reduce over m (protos), within quad
            const float om1 = __shfl_xor(m1, sh);
            const float om2 = __shfl_xor(m2, sh);
            const int   oid = __shfl_xor(id, sh);
            if (om1 > m1) { m2 = fmaxf(m1, om2); m1 = om1; id = oid; }
            else { if (om1 == m1 && oid < id) id = oid; m2 = fmaxf(m2, om1); }
        }
        const int posg = b * HW + pos0 + w * 16 + quad * 4 + r;
        if (m == 0) {
            out[OUT_ASSIGN + posg] = (float)id;
            if (m1 - m2 < GAP_THRESH) {          // near-tie -> exact fp64 recheck
                const int slot = atomicAdd(counter, 1);
                if (slot < MAXSUS) suspects[slot] = posg;
            }
        }
        // pass 2: softmax denominator and weighted sum (all lanes hold m1)
        float se = 0.f, sw = 0.f;
#pragma unroll
        for (int nt = 0; nt < 16; ++nt) {
            if (vbits & (1 << nt)) {
                const float d = acc[nt][r];
                const float e = __expf(d - m1);
                se += e; sw = fmaf(e, d, sw);
            }
        }
#pragma unroll
        for (int sh = 1; sh < 16; sh <<= 1) {
            se += __shfl_xor(se, sh);
            sw += __shfl_xor(sw, sh);
        }
        if (m == 0) out[posg] = sw / se;
    }
}

// ---------------------------------------------------------------------------
// Recheck: exact fp64 argmax for near-tie positions. Batches 16 suspects per
// block iteration: q columns staged to LDS in parallel, protos streamed once
// per batch. First-occurrence tie-break like jnp.argmax.
// ---------------------------------------------------------------------------
__global__ __launch_bounds__(256)
void recheck_kernel(const float* __restrict__ qry, const double* __restrict__ pn64,
                    const int* __restrict__ valid, const int* __restrict__ counter,
                    const int* __restrict__ suspects, float* __restrict__ out)
{
    __shared__ float  qsh[16][256];
    __shared__ double pd[4];
    __shared__ int    pi[4];
    const int t = threadIdx.x;
    const int w = t >> 6, l = t & 63;
    int n = *counter; if (n > MAXSUS) n = MAXSUS;
    const int nb = (n + 15) >> 4;

    for (int batch = blockIdx.x; batch < nb; batch += gridDim.x) {
        const int base = batch * 16;
        const int cnt = (n - base < 16) ? (n - base) : 16;
        for (int s = 0; s < cnt; ++s) {
            const int pos = suspects[base + s];
            qsh[s][t] = qry[(size_t)(pos >> 12) * (C * HW) + (size_t)t * HW + (pos & (HW - 1))];
        }
        __syncthreads();

        double acc[16];
#pragma unroll
        for (int s = 0; s < 16; ++s) acc[s] = 0.0;
        const double* pr = pn64 + (size_t)t * C;   // thread t = proto t
#pragma unroll 4
        for (int c = 0; c < C; ++c) {
            const double pv = pr[c];
#pragma unroll
            for (int s = 0; s < 16; ++s) acc[s] = fma((double)qsh[s][c], pv, acc[s]);
        }
        const bool vl = valid[t] != 0;
        for (int s = 0; s < cnt; ++s) {
            double dv = vl ? acc[s] : -INFINITY;
            int id = t;
#pragma unroll
            for (int sh = 1; sh < 64; sh <<= 1) {
                const double od = __shfl_xor(dv, sh);
                const int    oi = __shfl_xor(id, sh);
                if (od > dv || (od == dv && oi < id)) { dv = od; id = oi; }
            }
            if (l == 0) { pd[w] = dv; pi[w] = id; }
            __syncthreads();
            if (t == 0) {
                double bd = pd[0]; int bi = pi[0];
                for (int ww = 1; ww < 4; ++ww)
                    if (pd[ww] > bd || (pd[ww] == bd && pi[ww] < bi)) { bd = pd[ww]; bi = pi[ww]; }
                out[OUT_ASSIGN + suspects[base + s]] = (float)bi;
            }
            __syncthreads();
        }
    }
}

// ---------------------------------------------------------------------------
extern "C" void kernel_launch(void* const* d_in, const int* in_sizes, int n_in,
                              void* d_out, int out_size, void* d_ws, size_t ws_size,
                              hipStream_t stream)
{
    const float* qry   = (const float*)d_in[0];
    const float* sup_x = (const float*)d_in[1];
    const float* sup_y = (const float*)d_in[2];
    float* out = (float*)d_out;
    char*  ws  = (char*)d_ws;

    // ws layout (~1.03 MiB total)
    unsigned short* pB       = (unsigned short*)(ws);            // 256 KiB frag-order split-bf16 protos
    double*         pn64     = (double*)(ws + 256 * 1024);       // 512 KiB
    int*            valid    = (int*)(ws + 768 * 1024);          // 1 KiB
    int*            counter  = (int*)(ws + 768 * 1024 + 1024);   // 4 B
    int*            suspects = (int*)(ws + 768 * 1024 + 2048);   // 256 KiB

    prep_kernel<<<dim3(P), dim3(256), 0, stream>>>(sup_x, sup_y, out, pB, pn64, valid, counter);
    dist_kernel<<<dim3(BQ * (HW / 64)), dim3(256), 0, stream>>>(qry, pB, valid, out, counter, suspects);
    recheck_kernel<<<dim3(256), dim3(256), 0, stream>>>(qry, pn64, valid, counter, suspects, out);
}

// Round 4
// 302.265 us; speedup vs baseline: 1.0263x; 1.0263x over previous
//
#include <hip/hip_runtime.h>
#include <math.h>

// Problem constants
constexpr int BQ = 32;       // query batch
constexpr int C  = 256;      // channels
constexpr int HW = 4096;     // 64*64
constexpr int W  = 64;
constexpr int P  = 256;      // protos (4 * 8 * 8)
constexpr float THRESH = 0.95f;
constexpr float SCALE  = 20.0f;
constexpr float EPSF   = 1e-4f;
constexpr double EPSD  = 1e-4;
constexpr float GAP_THRESH = 2e-3f;   // split-bf16 dist err ~5e-4 -> 4x margin
constexpr int MAXSUS = 65536;

// d_out layout: pred [0, 131072) | debug_assign [131072, 262144) | proto_grid [262144, 278528)
constexpr int OUT_ASSIGN = BQ * HW;
constexpr int OUT_GRID   = 2 * BQ * HW;

typedef __attribute__((ext_vector_type(8))) short short8;
typedef __attribute__((ext_vector_type(4))) float floatx4;

static __device__ __forceinline__ unsigned short f2bf(float x) {
    unsigned u = __float_as_uint(x);
    u += 0x7FFFu + ((u >> 16) & 1u);     // round-to-nearest-even (no NaN inputs)
    return (unsigned short)(u >> 16);
}
static __device__ __forceinline__ float bf2f(unsigned short h) {
    return __uint_as_float(((unsigned)h) << 16);
}

// Fragment-order offset (ushort units): [tile][ks][h][lane][j], lane = quad*16 + idx,
// element j of lane <-> k = ks*32 + quad*8 + j. A and B use the IDENTICAL map, so
// any k-permutation cancels in the MFMA contraction.
#define FRAGOFF(tile, ks, h, lane) (((((tile) * 8 + (ks)) * 2 + (h)) * 64 + (lane)) * 8)

// async global->LDS, 16 B/lane; LDS dest = wave-uniform base + lane*16
static __device__ __forceinline__ void gl_lds16(const unsigned short* gp, unsigned short* lp) {
    __builtin_amdgcn_global_load_lds(
        (const __attribute__((address_space(1))) unsigned int*)gp,
        (__attribute__((address_space(3))) unsigned int*)lp, 16, 0, 0);
}

// ---------------------------------------------------------------------------
// Prep: pooled protos (fp64 normalize) -> split-bf16 frag-order pB + fp64 pn64,
// valid flags, proto_grid output, zero suspect counter. Block=proto, thread=channel.
// ---------------------------------------------------------------------------
__global__ __launch_bounds__(256)
void prep_kernel(const float* __restrict__ sup_x, const float* __restrict__ sup_y,
                 float* __restrict__ out, unsigned short* __restrict__ pB,
                 double* __restrict__ pn64, int* __restrict__ valid,
                 int* __restrict__ counter)
{
    const int p = blockIdx.x;     // proto index = s*64 + gy*8 + gx
    const int t = threadIdx.x;    // channel
    const int s = p >> 6, gy = (p >> 3) & 7, gx = p & 7;

    const float* base = sup_x + ((size_t)(s * C + t)) * HW + (gy * 8) * W + gx * 8;
    double sum = 0.0;
#pragma unroll
    for (int r = 0; r < 8; ++r) {
        const float4 a  = *(const float4*)(base + r * W);
        const float4 bq = *(const float4*)(base + r * W + 4);
        sum += (double)a.x;  sum += (double)a.y;  sum += (double)a.z;  sum += (double)a.w;
        sum += (double)bq.x; sum += (double)bq.y; sum += (double)bq.z; sum += (double)bq.w;
    }
    const double mean = sum * (1.0 / 64.0);

    __shared__ double red[256];
    red[t] = mean * mean;
    __syncthreads();
    for (int off = 128; off > 0; off >>= 1) {
        if (t < off) red[t] += red[t + off];
        __syncthreads();
    }
    const double nrm = sqrt(red[0]);
    const double pnv = mean / fmax(nrm, EPSD);
    pn64[(size_t)p * C + t] = pnv;

    // split-bf16 frag-order store: nt=p>>4, n-idx=p&15; ks=c>>5, quad=(c>>3)&3, j=c&7
    const float pnf = (float)pnv;
    const unsigned short phi = f2bf(pnf);
    const unsigned short plo = f2bf(pnf - bf2f(phi));
    const int nt = p >> 4, ks = t >> 5, lane = (((t >> 3) & 3) << 4) | (p & 15), j = t & 7;
    pB[FRAGOFF(nt, ks, 0, lane) + j] = phi;
    pB[FRAGOFF(nt, ks, 1, lane) + j] = plo;

    bool mybit = false;
    if (t < 64) {
        const int r = t >> 3, k = t & 7;
        mybit = sup_y[s * HW + (gy * 8 + r) * W + gx * 8 + k] > THRESH;
    }
    const unsigned long long bm = __ballot(mybit);   // wave 0 carries t=0..63
    if (t == 0) {
        valid[p] = (__popcll(bm) > 32) ? 1 : 0;      // mask_pooled > 0.5
        if (p == 0) *counter = 0;
    }
    if (t < 64) {
        const int i = p * 64 + t;
        out[OUT_GRID + i] = (sup_y[i] > THRESH) ? 1.0f : 0.0f;
    }
}

// ---------------------------------------------------------------------------
// Main: split-bf16 MFMA dists + fused softmax/argmax/pred.
//
// R4: B-REUSE x2 (LDS-port-bound fix). R2's counters (87us, MfmaUtil 23,
// occupancy 37, conflicts 0) put the LDS read port at ~60% of wall time:
// wave tile 16pos x 256protos re-reads the whole 32KiB B chunk per wave
// (2 ds_read_b128 per 3 MFMA). Now: block = 128 pos, wave owns 32 pos
// (2 pos-tiles) x 256 protos -> 6 MFMA per bh/bl pair -> per-CU LDS read
// demand halves (41 -> 20.5 us) and per-pos staging writes halve. Cost:
// acc = 128 AGPR -> ~200 unified regs -> launch_bounds(256,2), occupancy
// 37 -> ~25%. Favorable because the port, not wave count, binds; each SIMD
// hosts waves of DIFFERENT blocks (uncorrelated barriers).
// R3's counted-vmcnt + sched pins are REVERTED (they spilled: WRITE_SIZE
// 3->61 MB, dist 87->108). Plain __syncthreads only; no inline asm.
// A(ks+1) prefetch issues at the TOP of iter ks (double-buffered vbuf,
// compile-time indices) so the loads are older when barrier (b) drains.
// Spill tripwire: WRITE_SIZE > 20 MB.
// ---------------------------------------------------------------------------
__global__ __launch_bounds__(256, 2)
void dist_kernel(const float* __restrict__ qry, const unsigned short* __restrict__ pB,
                 const int* __restrict__ valid, float* __restrict__ out,
                 int* __restrict__ counter, int* __restrict__ suspects)
{
    __shared__ unsigned short ldsB[16 * 2 * 64 * 8];   // 32 KiB: [nt][h][lane][j]
    __shared__ int validLds[P];                        // 1 KiB

    const int t    = threadIdx.x;
    const int w    = t >> 6;      // wave
    const int l    = t & 63;
    const int quad = l >> 4;
    const int m    = l & 15;

    const int b    = blockIdx.x >> 5;            // 1024 blocks = 32 batch x 32 pos-chunks
    const int pos0 = (blockIdx.x & 31) * 128;

    validLds[t] = valid[t];

    // wave w owns pos-tiles at pos0 + w*32 (+0 and +16); lane covers
    // pos = base + m, k = ks*32 + quad*8 + j
    const float* qp0 = qry + (size_t)b * C * HW + pos0 + w * 32 + m;
    const float* qp1 = qp0 + 16;

    floatx4 acc[2][16];
#pragma unroll
    for (int p2 = 0; p2 < 2; ++p2)
#pragma unroll
        for (int nt = 0; nt < 16; ++nt) acc[p2][nt] = (floatx4){0.f, 0.f, 0.f, 0.f};

    // double-buffered A prefetch: vbuf[ks&1] holds A(ks), prefetch fills (ks+1)&1
    float vbuf[2][2][8];   // [parity][pos-tile][j]  (all indices compile-time after unroll)
#pragma unroll
    for (int j = 0; j < 8; ++j) {
        vbuf[0][0][j] = qp0[(size_t)(quad * 8 + j) * HW];
        vbuf[0][1][j] = qp1[(size_t)(quad * 8 + j) * HW];
    }

    float ssq0 = 0.f, ssq1 = 0.f;
#pragma unroll
    for (int ks = 0; ks < 8; ++ks) {
        __syncthreads();                 // (a) all waves done reading ldsB(ks-1); iter0: validLds
        // prefetch A(ks+1) FIRST (oldest possible issue; drained at barrier (b))
        if (ks < 7) {
#pragma unroll
            for (int j = 0; j < 8; ++j) {
                vbuf[(ks + 1) & 1][0][j] = qp0[(size_t)((ks + 1) * 32 + quad * 8 + j) * HW];
                vbuf[(ks + 1) & 1][1][j] = qp1[(size_t)((ks + 1) * 32 + quad * 8 + j) * HW];
            }
        }
        // stage B(ks): 32 chunks of 1 KiB; wave w stages chunks w*8..w*8+7
#pragma unroll
        for (int i = 0; i < 8; ++i) {
            const int idx = w * 8 + i, nt = idx >> 1, h = idx & 1;
            gl_lds16(pB + FRAGOFF(nt, ks, h, 0) + l * 8,
                     &ldsB[(nt * 2 + h) * 512]);
        }
        // convert A(ks) for both pos-tiles (VALU overlaps the B-stage flight)
        short8 h80, l80, h81, l81;
#pragma unroll
        for (int j = 0; j < 8; ++j) {
            const float v0 = vbuf[ks & 1][0][j];
            const float v1 = vbuf[ks & 1][1][j];
            ssq0 = fmaf(v0, v0, ssq0);
            ssq1 = fmaf(v1, v1, ssq1);
            const unsigned short hi0 = f2bf(v0);
            const unsigned short hi1 = f2bf(v1);
            h80[j] = (short)hi0;  l80[j] = (short)f2bf(v0 - bf2f(hi0));
            h81[j] = (short)hi1;  l81[j] = (short)f2bf(v1 - bf2f(hi1));
        }
        __syncthreads();                 // (b) vmcnt drained -> B(ks) visible
#pragma unroll
        for (int nt = 0; nt < 16; ++nt) {
            const short8 bh = *(const short8*)&ldsB[((nt * 2 + 0) * 64 + l) * 8];
            const short8 bl = *(const short8*)&ldsB[((nt * 2 + 1) * 64 + l) * 8];
            acc[0][nt] = __builtin_amdgcn_mfma_f32_16x16x32_bf16(h80, bh, acc[0][nt], 0, 0, 0);
            acc[0][nt] = __builtin_amdgcn_mfma_f32_16x16x32_bf16(h80, bl, acc[0][nt], 0, 0, 0);
            acc[0][nt] = __builtin_amdgcn_mfma_f32_16x16x32_bf16(l80, bh, acc[0][nt], 0, 0, 0);
            acc[1][nt] = __builtin_amdgcn_mfma_f32_16x16x32_bf16(h81, bh, acc[1][nt], 0, 0, 0);
            acc[1][nt] = __builtin_amdgcn_mfma_f32_16x16x32_bf16(h81, bl, acc[1][nt], 0, 0, 0);
            acc[1][nt] = __builtin_amdgcn_mfma_f32_16x16x32_bf16(l81, bh, acc[1][nt], 0, 0, 0);
        }
    }

    // ||q||^2: sum the 4 quads (lanes differing in bits 4,5)
    ssq0 += __shfl_xor(ssq0, 16);
    ssq0 += __shfl_xor(ssq0, 32);
    ssq1 += __shfl_xor(ssq1, 16);
    ssq1 += __shfl_xor(ssq1, 32);
    const float scale0 = SCALE / fmaxf(sqrtf(ssq0), EPSF);
    const float scale1 = SCALE / fmaxf(sqrtf(ssq1), EPSF);

    // ---- epilogue (wave-local). C/D: proto = nt*16 + m, pos-in-tile = quad*4 + r ----
    int vbits = 0;
#pragma unroll
    for (int nt = 0; nt < 16; ++nt) vbits |= validLds[nt * 16 + m] << nt;

#pragma unroll
    for (int p2 = 0; p2 < 2; ++p2) {
        const float scalev = (p2 == 0) ? scale0 : scale1;
        float scr[4];
#pragma unroll
        for (int r = 0; r < 4; ++r) scr[r] = __shfl(scalev, quad * 4 + r);
#pragma unroll
        for (int nt = 0; nt < 16; ++nt)
#pragma unroll
            for (int r = 0; r < 4; ++r) acc[p2][nt][r] *= scr[r];   // positive: ordering-safe

#pragma unroll
        for (int r = 0; r < 4; ++r) {
            // pass 1: max / argmax (first occurrence) / 2nd-max
            float m1 = -INFINITY, m2 = -INFINITY; int id = 0x7fffffff;
#pragma unroll
            for (int nt = 0; nt < 16; ++nt) {
                if (vbits & (1 << nt)) {
                    const float d = acc[p2][nt][r];
                    if (d > m1)      { m2 = m1; m1 = d; id = nt * 16 + m; }
                    else if (d > m2) { m2 = d; }
                }
            }
#pragma unroll
            for (int sh = 1; sh < 16; sh <<= 1) {   // reduce over m (protos), within quad
                const float om1 = __shfl_xor(m1, sh);
                const float om2 = __shfl_xor(m2, sh);
                const int   oid = __shfl_xor(id, sh);
                if (om1 > m1) { m2 = fmaxf(m1, om2); m1 = om1; id = oid; }
                else { if (om1 == m1 && oid < id) id = oid; m2 = fmaxf(m2, om1); }
            }
            const int posg = b * HW + pos0 + w * 32 + p2 * 16 + quad * 4 + r;
            if (m == 0) {
                out[OUT_ASSIGN + posg] = (float)id;
                if (m1 - m2 < GAP_THRESH) {          // near-tie -> exact fp64 recheck
                    const int slot = atomicAdd(counter, 1);
                    if (slot < MAXSUS) suspects[slot] = posg;
                }
            }
            // pass 2: softmax denominator and weighted sum (all lanes hold m1)
            float se = 0.f, sw = 0.f;
#pragma unroll
            for (int nt = 0; nt < 16; ++nt) {
                if (vbits & (1 << nt)) {
                    const float d = acc[p2][nt][r];
                    const float e = __expf(d - m1);
                    se += e; sw = fmaf(e, d, sw);
                }
            }
#pragma unroll
            for (int sh = 1; sh < 16; sh <<= 1) {
                se += __shfl_xor(se, sh);
                sw += __shfl_xor(sw, sh);
            }
            if (m == 0) out[posg] = sw / se;
        }
    }
}

// ---------------------------------------------------------------------------
// Recheck: exact fp64 argmax for near-tie positions. Batches 16 suspects per
// block iteration: q columns staged to LDS in parallel, protos streamed once
// per batch. First-occurrence tie-break like jnp.argmax.
// ---------------------------------------------------------------------------
__global__ __launch_bounds__(256)
void recheck_kernel(const float* __restrict__ qry, const double* __restrict__ pn64,
                    const int* __restrict__ valid, const int* __restrict__ counter,
                    const int* __restrict__ suspects, float* __restrict__ out)
{
    __shared__ float  qsh[16][256];
    __shared__ double pd[4];
    __shared__ int    pi[4];
    const int t = threadIdx.x;
    const int w = t >> 6, l = t & 63;
    int n = *counter; if (n > MAXSUS) n = MAXSUS;
    const int nb = (n + 15) >> 4;

    for (int batch = blockIdx.x; batch < nb; batch += gridDim.x) {
        const int base = batch * 16;
        const int cnt = (n - base < 16) ? (n - base) : 16;
        for (int s = 0; s < cnt; ++s) {
            const int pos = suspects[base + s];
            qsh[s][t] = qry[(size_t)(pos >> 12) * (C * HW) + (size_t)t * HW + (pos & (HW - 1))];
        }
        __syncthreads();

        double acc[16];
#pragma unroll
        for (int s = 0; s < 16; ++s) acc[s] = 0.0;
        const double* pr = pn64 + (size_t)t * C;   // thread t = proto t
#pragma unroll 4
        for (int c = 0; c < C; ++c) {
            const double pv = pr[c];
#pragma unroll
            for (int s = 0; s < 16; ++s) acc[s] = fma((double)qsh[s][c], pv, acc[s]);
        }
        const bool vl = valid[t] != 0;
        for (int s = 0; s < cnt; ++s) {
            double dv = vl ? acc[s] : -INFINITY;
            int id = t;
#pragma unroll
            for (int sh = 1; sh < 64; sh <<= 1) {
                const double od = __shfl_xor(dv, sh);
                const int    oi = __shfl_xor(id, sh);
                if (od > dv || (od == dv && oi < id)) { dv = od; id = oi; }
            }
            if (l == 0) { pd[w] = dv; pi[w] = id; }
            __syncthreads();
            if (t == 0) {
                double bd = pd[0]; int bi = pi[0];
                for (int ww = 1; ww < 4; ++ww)
                    if (pd[ww] > bd || (pd[ww] == bd && pi[ww] < bi)) { bd = pd[ww]; bi = pi[ww]; }
                out[OUT_ASSIGN + suspects[base + s]] = (float)bi;
            }
            __syncthreads();
        }
    }
}

// ---------------------------------------------------------------------------
extern "C" void kernel_launch(void* const* d_in, const int* in_sizes, int n_in,
                              void* d_out, int out_size, void* d_ws, size_t ws_size,
                              hipStream_t stream)
{
    const float* qry   = (const float*)d_in[0];
    const float* sup_x = (const float*)d_in[1];
    const float* sup_y = (const float*)d_in[2];
    float* out = (float*)d_out;
    char*  ws  = (char*)d_ws;

    // ws layout (~1.03 MiB total)
    unsigned short* pB       = (unsigned short*)(ws);            // 256 KiB frag-order split-bf16 protos
    double*         pn64     = (double*)(ws + 256 * 1024);       // 512 KiB
    int*            valid    = (int*)(ws + 768 * 1024);          // 1 KiB
    int*            counter  = (int*)(ws + 768 * 1024 + 1024);   // 4 B
    int*            suspects = (int*)(ws + 768 * 1024 + 2048);   // 256 KiB

    prep_kernel<<<dim3(P), dim3(256), 0, stream>>>(sup_x, sup_y, out, pB, pn64, valid, counter);
    dist_kernel<<<dim3(BQ * (HW / 128)), dim3(256), 0, stream>>>(qry, pB, valid, out, counter, suspects);
    recheck_kernel<<<dim3(256), dim3(256), 0, stream>>>(qry, pn64, valid, counter, suspects, out);
}